// Round 1
// baseline (272.315 us; speedup 1.0000x reference)
//
#include <hip/hip_runtime.h>

#define HDIM 4096
#define NIN 17
#define NA 4

// ---- config ----
constexpr int TB = 256;                 // threads per block
constexpr int CPT = 4;                  // columns per thread (one float4)
constexpr int BXC = HDIM / (TB * CPT);  // 4 column groups
constexpr int NCHUNK = 256;             // row chunks
constexpr int RPC = HDIM / NCHUNK;      // 16 rows per chunk
constexpr size_t NELEM = (size_t)HDIM * HDIM;

// Kernel A: partial sums of hidden @ (w + alpha*hebb) over row chunks.
// __launch_bounds__(256, 4): grid is 1024 blocks = 4 blocks/CU = 16 waves/CU max,
// so capping at 4 waves/EU (128 VGPR) costs no occupancy but lets the compiler
// keep ~24 float4 loads in flight per wave (vs 32-VGPR starvation before).
__global__ __launch_bounds__(TB, 4)
void k_matvec(const float* __restrict__ w, const float* __restrict__ alpha,
              const float* __restrict__ hebb, const float* __restrict__ hidden,
              float* __restrict__ partial, float* __restrict__ acc5) {
    // zero the head-dot accumulators (k_hact atomicAdds into them later)
    if (blockIdx.x == 0 && blockIdx.y == 0 && threadIdx.x < 8) acc5[threadIdx.x] = 0.f;

    const int col0 = (blockIdx.x * TB + threadIdx.x) * CPT;
    const int row0 = blockIdx.y * RPC;
    const size_t base = (size_t)row0 * HDIM + col0;
    const float* __restrict__ wp = w + base;
    const float* __restrict__ ap = alpha + base;
    const float* __restrict__ bp = hebb + base;
    float4 acc = make_float4(0.f, 0.f, 0.f, 0.f);
#pragma unroll 8
    for (int r = 0; r < RPC; ++r) {
        const float hv = hidden[row0 + r];
        const size_t off = (size_t)r * HDIM;
        const float4 wv = *(const float4*)(wp + off);
        const float4 av = *(const float4*)(ap + off);
        const float4 bv = *(const float4*)(bp + off);
        acc.x += hv * (wv.x + av.x * bv.x);
        acc.y += hv * (wv.y + av.y * bv.y);
        acc.z += hv * (wv.z + av.z * bv.z);
        acc.w += hv * (wv.w + av.w * bv.w);
    }
    *(float4*)(partial + (size_t)blockIdx.y * HDIM + col0) = acc;
}

// Kernel B: reduce partials, add i2h(x)+bias, tanh -> h; fused head partial dots.
__global__ __launch_bounds__(256)
void k_hact(const float* __restrict__ partial, const float* __restrict__ x,
            const float* __restrict__ i2h_w, const float* __restrict__ i2h_b,
            const float* __restrict__ h2o_w, const float* __restrict__ h2v_w,
            float* __restrict__ h_f, float* __restrict__ h_out,
            float* __restrict__ acc5) {
    const int tid = threadIdx.x;
    const int j = blockIdx.x * 256 + tid;
    float s = 0.f;
#pragma unroll 16
    for (int c = 0; c < NCHUNK; ++c) s += partial[(size_t)c * HDIM + j];
    float z = i2h_b[j] + s;
#pragma unroll
    for (int k = 0; k < NIN; ++k) z += x[k] * i2h_w[j * NIN + k];
    const float h = tanhf(z);
    h_f[j] = h;
    h_out[j] = h;

    // fused head dot-product partials: 4 policy rows + 1 value row
    float d[NA + 1];
#pragma unroll
    for (int a = 0; a < NA; ++a) d[a] = h * h2o_w[(size_t)a * HDIM + j];
    d[NA] = h * h2v_w[j];

    __shared__ float red[256];
#pragma unroll
    for (int a = 0; a < NA + 1; ++a) {
        red[tid] = d[a];
        __syncthreads();
        for (int sft = 128; sft > 0; sft >>= 1) {
            if (tid < sft) red[tid] += red[tid + sft];
            __syncthreads();
        }
        if (tid == 0) atomicAdd(acc5 + a, red[0]);
        __syncthreads();
    }
}

// Kernel C: hebb_new = (1-eta)*hebb + eta*outer(hidden, h).
// hebb_out = out + 4101 floats is only 4B-aligned; shift the thread map by +3 so
// each thread owns elements s..s+3 with s = 4t+3 -> (4101+s) % 4 == 0 -> the
// STORE is one aligned float4 (1 KB/wave-instr). The hebb read becomes one
// scalar (same cacheline as neighbor lane's vector) + one aligned float4.
__global__ __launch_bounds__(256)
void k_hebb(const float* __restrict__ hebb, const float* __restrict__ hidden,
            const float* __restrict__ h_f, const float* __restrict__ eta,
            float* __restrict__ hebb_out) {
    const size_t t = (size_t)blockIdx.x * 256 + threadIdx.x;
    const size_t s = 4 * t + 3;
    const float e = eta[0];
    const float om = 1.f - e;

    if (t == 0) {  // head elements 0,1,2 (row 0)
        const float hv0 = e * hidden[0];
        hebb_out[0] = om * hebb[0] + hv0 * h_f[0];
        hebb_out[1] = om * hebb[1] + hv0 * h_f[1];
        hebb_out[2] = om * hebb[2] + hv0 * h_f[2];
    }

    if (s + 3 < NELEM) {
        const float b0 = hebb[s];                           // 4B-aligned scalar
        const float4 bv = *(const float4*)(hebb + s + 1);   // 16B-aligned
        const float b[4] = {b0, bv.x, bv.y, bv.z};
        float v[4];
#pragma unroll
        for (int k = 0; k < 4; ++k) {
            const size_t m = s + (size_t)k;
            const int i = (int)(m >> 12);           // row (may change mid-vector)
            const int jj = (int)(m & (HDIM - 1));   // col
            v[k] = om * b[k] + e * hidden[i] * h_f[jj];
        }
        *(float4*)(hebb_out + s) = make_float4(v[0], v[1], v[2], v[3]);  // 16B-aligned
    } else {
        for (size_t m = s; m < NELEM; ++m) {        // tail element N-1
            const int i = (int)(m >> 12);
            const int jj = (int)(m & (HDIM - 1));
            hebb_out[m] = om * hebb[m] + e * hidden[i] * h_f[jj];
        }
    }
}

// Kernel D: tiny finalize — softmax over 4 accumulated dots + value head.
__global__ __launch_bounds__(64)
void k_finish(const float* __restrict__ acc5,
              const float* __restrict__ h2o_b, const float* __restrict__ h2v_b,
              float* __restrict__ out) {
    if (threadIdx.x == 0) {
        float o[NA];
        float mx = -1e30f;
#pragma unroll
        for (int a = 0; a < NA; ++a) { o[a] = acc5[a] + h2o_b[a]; mx = fmaxf(mx, o[a]); }
        float se = 0.f;
#pragma unroll
        for (int a = 0; a < NA; ++a) { o[a] = __expf(o[a] - mx); se += o[a]; }
#pragma unroll
        for (int a = 0; a < NA; ++a) out[a] = o[a] / se;
        out[NA] = acc5[NA] + h2v_b[0];
    }
}

extern "C" void kernel_launch(void* const* d_in, const int* in_sizes, int n_in,
                              void* d_out, int out_size, void* d_ws, size_t ws_size,
                              hipStream_t stream) {
    const float* x      = (const float*)d_in[0];
    const float* hidden = (const float*)d_in[1];
    const float* hebb   = (const float*)d_in[2];
    const float* i2h_w  = (const float*)d_in[3];
    const float* i2h_b  = (const float*)d_in[4];
    const float* w      = (const float*)d_in[5];
    const float* alpha  = (const float*)d_in[6];
    const float* eta    = (const float*)d_in[7];
    const float* h2o_w  = (const float*)d_in[8];
    const float* h2o_b  = (const float*)d_in[9];
    const float* h2v_w  = (const float*)d_in[10];
    const float* h2v_b  = (const float*)d_in[11];
    float* out = (float*)d_out;

    float* partial = (float*)d_ws;                    // NCHUNK*HDIM floats (4 MB)
    float* h_f  = partial + (size_t)NCHUNK * HDIM;    // HDIM floats
    float* acc5 = h_f + HDIM;                         // 8 floats (5 used)

    // out layout: activout[4] | valueout[1] | h[4096] | hebb_new[4096*4096]
    float* h_out    = out + 5;
    float* hebb_out = out + 5 + HDIM;

    k_matvec<<<dim3(BXC, NCHUNK), TB, 0, stream>>>(w, alpha, hebb, hidden, partial, acc5);
    k_hact<<<HDIM / 256, 256, 0, stream>>>(partial, x, i2h_w, i2h_b, h2o_w, h2v_w, h_f, h_out, acc5);
    k_hebb<<<(int)((NELEM / 4) / 256), 256, 0, stream>>>(hebb, hidden, h_f, eta, hebb_out);
    k_finish<<<1, 64, 0, stream>>>(acc5, h2o_b, h2v_b, out);
}